// Round 9
// baseline (232.553 us; speedup 1.0000x reference)
//
#include <hip/hip_runtime.h>

typedef float v2f __attribute__((ext_vector_type(2)));

#define NEG_INF (-__builtin_huge_valf())

#define CCH   4                 // c's per LDS chunk
#define HB    4                 // output h rows per block tile
#define ROWS  (HB + 2)          // 6 (h halo)
#define XSTR  64                // xs row stride: pure float4 data, b128-balanced
#define SLOTS 3                 // CCH*ROWS*16 float4 / 128 threads

// DPP row-shifts (16-lane rows). bound_ctrl=0 keeps `old` for invalid source
// lanes: old=-inf gives the w-halo for free (wg==0 / wg==15). No LDS edges.
__device__ __forceinline__ float dpp_shr1(float v, float old) {   // lane wg <- wg-1
    return __int_as_float(__builtin_amdgcn_update_dpp(
        __float_as_int(old), __float_as_int(v), 0x111, 0xF, 0xF, false));
}
__device__ __forceinline__ float dpp_shl1(float v, float old) {   // lane wg <- wg+1
    return __int_as_float(__builtin_amdgcn_update_dpp(
        __float_as_int(old), __float_as_int(v), 0x101, 0xF, 0xF, false));
}

// 2-wave blocks sharing staged x: block = 128 threads, tile = 4o x 4h x 64w,
// wave wv computes o pair (o_base + 2*wv + {0,1}); per-thread 2o x 4w = 8 acc.
// Grid (16,8,16) = 2048 blocks = 4096 waves; LDS 6144 B -> 16 blocks/CU =
// 32 waves/CU = 8 waves/SIMD (VGPR<=64 via __launch_bounds__(128,8)).
// Halves global x traffic vs 1-wave blocks (each staged byte serves 4 o's)
// AND doubles occupancy; barriers bind only 2 waves.
__global__ __launch_bounds__(128, 8)
void maxplus_conv2d_kernel(const float* __restrict__ x,
                           const float* __restrict__ kern,
                           float* __restrict__ out) {
    __shared__ float xs[CCH * ROWS * XSTR];   // 6144 B

    const int tid  = threadIdx.x;       // 0..127
    const int wv   = tid >> 6;          // wave 0/1
    const int lane = tid & 63;
    const int wg   = lane & 15;
    const int hr   = lane >> 4;         // 0..3
    const int w0   = wg << 2;

    const int h_base = blockIdx.x * HB;
    const int b      = blockIdx.y;
    const int o_base = (blockIdx.z << 2) + (wv << 1);   // this wave's o pair

    // ---- staging slots (chunk-invariant; computed once) ----
    const float* xb = x + (size_t)b * 64 * 64 * 64;
    const float* gsrc[SLOTS];
    float*       xdst[SLOTS];
    bool         vmask[SLOTS];
#pragma unroll
    for (int k = 0; k < SLOTS; ++k) {
        int it    = k * 128 + tid;        // 0..383
        int f4    = it & 15;
        int rowid = it >> 4;              // 0..23
        int cl    = rowid / ROWS;
        int r     = rowid - cl * ROWS;
        int gh    = h_base + r - 1;       // -1..64
        bool valid = (unsigned)gh < 64u;
        int  ghc   = valid ? gh : 0;      // clamped (no OOB); value replaced by -inf
        gsrc[k]  = xb + ((size_t)cl * 64 + ghc) * 64 + f4 * 4;
        xdst[k]  = &xs[rowid * XSTR + f4 * 4];   // aligned ds_write_b128
        vmask[k] = valid;
    }

    const float ninf = NEG_INF;

    float acc[2][4];
#pragma unroll
    for (int oo = 0; oo < 2; ++oo)
#pragma unroll
        for (int wi = 0; wi < 4; ++wi)
            acc[oo][wi] = NEG_INF;

    // prefetch chunk 0
    float4 R[SLOTS];
#pragma unroll
    for (int k = 0; k < SLOTS; ++k) R[k] = *(const float4*)gsrc[k];

#pragma unroll 1
    for (int cc = 0; cc < 64; cc += CCH) {
        __syncthreads();   // WAR: both waves done reading prev chunk

#pragma unroll
        for (int k = 0; k < SLOTS; ++k) {
            float4 v = R[k];
            if (!vmask[k]) v = make_float4(NEG_INF, NEG_INF, NEG_INF, NEG_INF);
            *(float4*)xdst[k] = v;
        }

        __syncthreads();   // RAW: staged chunk visible to both waves

        if (cc + CCH < 64) {   // prefetch next chunk; vmcnt rides under compute
#pragma unroll
            for (int k = 0; k < SLOTS; ++k) {
                gsrc[k] += CCH * 64 * 64;
                R[k] = *(const float4*)gsrc[k];
            }
        }

#pragma unroll
        for (int cl = 0; cl < CCH; ++cl) {
            // taps for this c, this wave's o pair: wave-uniform -> s_load (18 SGPRs)
            float kv[2][9];
#pragma unroll
            for (int oo = 0; oo < 2; ++oo) {
                const float* kp = kern + ((size_t)(o_base + oo) * 64 + (cc + cl)) * 9;
#pragma unroll
                for (int t = 0; t < 9; ++t) kv[oo][t] = kp[t];
            }

#pragma unroll
            for (int r = 0; r < 3; ++r) {
                const int rowid = cl * ROWS + hr + r;
                float4 m = *(const float4*)(&xs[rowid * XSTR + w0]);
                float le = dpp_shr1(m.w, ninf);   // col w0-1 (wg==0 -> -inf)
                float re = dpp_shl1(m.x, ninf);   // col w0+4 (wg==15 -> -inf)

                // window pairs (window idx 0..5 = [le, m.x..m.w, re])
                v2f P0 = {le,  m.x};   // idx (0,1)
                v2f P1 = {m.y, m.z};   // idx (2,3)
                v2f P2 = {m.w, re };   // idx (4,5)
                v2f Q0 = {m.x, m.y};   // idx (1,2)
                v2f Q1 = {m.z, m.w};   // idx (3,4)

#pragma unroll
                for (int oo = 0; oo < 2; ++oo) {
                    const float* k9 = kv[oo];
                    v2f ka = {k9[3*r+0], k9[3*r+0]};
                    v2f kb = {k9[3*r+1], k9[3*r+1]};
                    v2f kc = {k9[3*r+2], k9[3*r+2]};
                    v2f a0 = P0 + ka, b0 = P1 + ka;   // kj=0
                    v2f a1 = Q0 + kb, b1 = Q1 + kb;   // kj=1
                    v2f a2 = P1 + kc, b2 = P2 + kc;   // kj=2

                    acc[oo][0] = fmaxf(acc[oo][0], fmaxf(fmaxf(a0.x, a1.x), a2.x));
                    acc[oo][1] = fmaxf(acc[oo][1], fmaxf(fmaxf(a0.y, a1.y), a2.y));
                    acc[oo][2] = fmaxf(acc[oo][2], fmaxf(fmaxf(b0.x, b1.x), b2.x));
                    acc[oo][3] = fmaxf(acc[oo][3], fmaxf(fmaxf(b0.y, b1.y), b2.y));
                }
            }
        }
    }

    const int h = h_base + hr;
#pragma unroll
    for (int oo = 0; oo < 2; ++oo) {
        float4 v = make_float4(acc[oo][0], acc[oo][1], acc[oo][2], acc[oo][3]);
        *(float4*)(out + ((((size_t)b * 64 + (o_base + oo)) * 64 + h) * 64 + w0)) = v;
    }
}

extern "C" void kernel_launch(void* const* d_in, const int* in_sizes, int n_in,
                              void* d_out, int out_size, void* d_ws, size_t ws_size,
                              hipStream_t stream) {
    const float* x    = (const float*)d_in[0];   // [8,64,64,64]
    const float* kern = (const float*)d_in[1];   // [64,64,3,3]
    float* out = (float*)d_out;                  // [8,64,64,64]

    dim3 grid(16, 8, 16);   // h-tiles, b, o-quads (4 o's per block)
    dim3 block(128);
    maxplus_conv2d_kernel<<<grid, block, 0, stream>>>(x, kern, out);
}

// Round 10
// 115.134 us; speedup vs baseline: 2.0198x; 2.0198x over previous
//
#include <hip/hip_runtime.h>

typedef float v2f __attribute__((ext_vector_type(2)));

#define NEG_INF (-__builtin_huge_valf())

#define CCH   4                 // c's per LDS chunk
#define HB    4                 // output h rows per block tile
#define ROWS  (HB + 2)          // 6 (h halo)
#define XSTR  64                // xs row stride: pure float4 data, b128-balanced
#define SLOTS 3                 // CCH*ROWS*16 float4 / 128 threads

// DPP row-shifts (16-lane rows). bound_ctrl=0 keeps `old` for invalid source
// lanes: old=-inf gives the w-halo for free (wg==0 / wg==15). No LDS edges.
__device__ __forceinline__ float dpp_shr1(float v, float old) {   // lane wg <- wg-1
    return __int_as_float(__builtin_amdgcn_update_dpp(
        __float_as_int(old), __float_as_int(v), 0x111, 0xF, 0xF, false));
}
__device__ __forceinline__ float dpp_shl1(float v, float old) {   // lane wg <- wg+1
    return __int_as_float(__builtin_amdgcn_update_dpp(
        __float_as_int(old), __float_as_int(v), 0x101, 0xF, 0xF, false));
}

// 2-wave blocks sharing staged x: block = 128 threads, tile = 4o x 4h x 64w,
// wave wv computes o pair (o_base + 2*wv + {0,1}); per-thread 2o x 4w = 8 acc.
// Grid (16,8,16) = 2048 blocks = 4096 waves; LDS 6144 B -> 16 blocks/CU =
// 32 waves/CU = 8 waves/SIMD if VGPR <= 64.
//
// ROUND-9 BUG: __launch_bounds__(128,8) hard-capped VGPR at 64 with zero
// slack; allocator spilled gsrc/R/acc to scratch (VGPR_Count 32, WRITE_SIZE
// 340 MB, 183 µs). Bound relaxed to 4 (cap 128): natural footprint ~60 VGPR,
// occupancy self-limits at 7-8 waves/SIMD WITHOUT spills.
__global__ __launch_bounds__(128, 4)
void maxplus_conv2d_kernel(const float* __restrict__ x,
                           const float* __restrict__ kern,
                           float* __restrict__ out) {
    __shared__ float xs[CCH * ROWS * XSTR];   // 6144 B

    const int tid  = threadIdx.x;       // 0..127
    const int wv   = tid >> 6;          // wave 0/1
    const int lane = tid & 63;
    const int wg   = lane & 15;
    const int hr   = lane >> 4;         // 0..3
    const int w0   = wg << 2;

    const int h_base = blockIdx.x * HB;
    const int b      = blockIdx.y;
    const int o_base = (blockIdx.z << 2) + (wv << 1);   // this wave's o pair

    // ---- staging slots (chunk-invariant; computed once) ----
    const float* xb = x + (size_t)b * 64 * 64 * 64;
    const float* gsrc[SLOTS];
    float*       xdst[SLOTS];
    bool         vmask[SLOTS];
#pragma unroll
    for (int k = 0; k < SLOTS; ++k) {
        int it    = k * 128 + tid;        // 0..383
        int f4    = it & 15;
        int rowid = it >> 4;              // 0..23
        int cl    = rowid / ROWS;
        int r     = rowid - cl * ROWS;
        int gh    = h_base + r - 1;       // -1..64
        bool valid = (unsigned)gh < 64u;
        int  ghc   = valid ? gh : 0;      // clamped (no OOB); value replaced by -inf
        gsrc[k]  = xb + ((size_t)cl * 64 + ghc) * 64 + f4 * 4;
        xdst[k]  = &xs[rowid * XSTR + f4 * 4];   // aligned ds_write_b128
        vmask[k] = valid;
    }

    const float ninf = NEG_INF;

    float acc[2][4];
#pragma unroll
    for (int oo = 0; oo < 2; ++oo)
#pragma unroll
        for (int wi = 0; wi < 4; ++wi)
            acc[oo][wi] = NEG_INF;

    // prefetch chunk 0
    float4 R[SLOTS];
#pragma unroll
    for (int k = 0; k < SLOTS; ++k) R[k] = *(const float4*)gsrc[k];

#pragma unroll 1
    for (int cc = 0; cc < 64; cc += CCH) {
        __syncthreads();   // WAR: both waves done reading prev chunk

#pragma unroll
        for (int k = 0; k < SLOTS; ++k) {
            float4 v = R[k];
            if (!vmask[k]) v = make_float4(NEG_INF, NEG_INF, NEG_INF, NEG_INF);
            *(float4*)xdst[k] = v;
        }

        __syncthreads();   // RAW: staged chunk visible to both waves

        if (cc + CCH < 64) {   // prefetch next chunk; vmcnt rides under compute
#pragma unroll
            for (int k = 0; k < SLOTS; ++k) {
                gsrc[k] += CCH * 64 * 64;
                R[k] = *(const float4*)gsrc[k];
            }
        }

#pragma unroll
        for (int cl = 0; cl < CCH; ++cl) {
            // taps for this c, this wave's o pair: wave-uniform -> s_load
            float kv[2][9];
#pragma unroll
            for (int oo = 0; oo < 2; ++oo) {
                const float* kp = kern + ((size_t)(o_base + oo) * 64 + (cc + cl)) * 9;
#pragma unroll
                for (int t = 0; t < 9; ++t) kv[oo][t] = kp[t];
            }

#pragma unroll
            for (int r = 0; r < 3; ++r) {
                const int rowid = cl * ROWS + hr + r;
                float4 m = *(const float4*)(&xs[rowid * XSTR + w0]);
                float le = dpp_shr1(m.w, ninf);   // col w0-1 (wg==0 -> -inf)
                float re = dpp_shl1(m.x, ninf);   // col w0+4 (wg==15 -> -inf)

                // window pairs (window idx 0..5 = [le, m.x..m.w, re])
                v2f P0 = {le,  m.x};   // idx (0,1)
                v2f P1 = {m.y, m.z};   // idx (2,3)
                v2f P2 = {m.w, re };   // idx (4,5)
                v2f Q0 = {m.x, m.y};   // idx (1,2)
                v2f Q1 = {m.z, m.w};   // idx (3,4)

#pragma unroll
                for (int oo = 0; oo < 2; ++oo) {
                    const float* k9 = kv[oo];
                    v2f ka = {k9[3*r+0], k9[3*r+0]};
                    v2f kb = {k9[3*r+1], k9[3*r+1]};
                    v2f kc = {k9[3*r+2], k9[3*r+2]};
                    v2f a0 = P0 + ka, b0 = P1 + ka;   // kj=0
                    v2f a1 = Q0 + kb, b1 = Q1 + kb;   // kj=1
                    v2f a2 = P1 + kc, b2 = P2 + kc;   // kj=2

                    acc[oo][0] = fmaxf(acc[oo][0], fmaxf(fmaxf(a0.x, a1.x), a2.x));
                    acc[oo][1] = fmaxf(acc[oo][1], fmaxf(fmaxf(a0.y, a1.y), a2.y));
                    acc[oo][2] = fmaxf(acc[oo][2], fmaxf(fmaxf(b0.x, b1.x), b2.x));
                    acc[oo][3] = fmaxf(acc[oo][3], fmaxf(fmaxf(b0.y, b1.y), b2.y));
                }
            }
        }
    }

    const int h = h_base + hr;
#pragma unroll
    for (int oo = 0; oo < 2; ++oo) {
        float4 v = make_float4(acc[oo][0], acc[oo][1], acc[oo][2], acc[oo][3]);
        *(float4*)(out + ((((size_t)b * 64 + (o_base + oo)) * 64 + h) * 64 + w0)) = v;
    }
}

extern "C" void kernel_launch(void* const* d_in, const int* in_sizes, int n_in,
                              void* d_out, int out_size, void* d_ws, size_t ws_size,
                              hipStream_t stream) {
    const float* x    = (const float*)d_in[0];   // [8,64,64,64]
    const float* kern = (const float*)d_in[1];   // [64,64,3,3]
    float* out = (float*)d_out;                  // [8,64,64,64]

    dim3 grid(16, 8, 16);   // h-tiles, b, o-quads (4 o's per block)
    dim3 block(128);
    maxplus_conv2d_kernel<<<grid, block, 0, stream>>>(x, kern, out);
}